// Round 11
// baseline (718.277 us; speedup 1.0000x reference)
//
#include <hip/hip_runtime.h>

typedef unsigned short us_t;
typedef short bf16x8 __attribute__((ext_vector_type(8)));
typedef float f32x4 __attribute__((ext_vector_type(4)));

#define E_ACT 200000
#define E_TOT 250000
#define DIR   240
#define C_OLD 0.8944271909999159f
#define C_NEW 0.4472135954999579f
#define S_OH  0.08838834764831845f   // 1/sqrt(128)

// ---- transposed bf16 weight arena offsets (elements) ----
#define WO_W0   0         // [160][352]
#define WO_W1P  56320     // [48][288]
#define WO_W1M  70144     // [48][288]
#define WO_W2P  83968     // [16][96]
#define WO_W2M  85504     // [16][96]
#define WO_GW   87040     // [224][128]
#define WO_EW   115712    // [112][128]
#define WO_A1   130048    // [128][192]
#define WO_A2   154624    // [128][128]
#define WO_A3   171008    // [128][128]
#define WO_B1   187392    // [128][256]
#define WO_B2   220160    // [128][128]
#define WO_B3   236544    // [128][128]
#define WO_O0   252928    // [64][128]
#define WO_O1   261120    // [32][128]
#define WO_O2   265216    // [16][128]
#define WO_P0T  267264    // [64][64]
#define WO_P1T  271360    // [32][32]
#define WO_P2T  272384    // [16][32] (k 16..31 zeroed)
#define W_TOTAL 272896

__device__ __forceinline__ float b2f(us_t u) { return __uint_as_float(((unsigned)u) << 16); }
__device__ __forceinline__ us_t f2b(float f) {
    unsigned x = __float_as_uint(f);
    return (us_t)((x + 0x7fffu + ((x >> 16) & 1u)) >> 16);   // RNE
}
__device__ __forceinline__ float sigm(float x) { return 1.0f / (1.0f + __expf(-x)); }

#define MFMA(a,b,c) __builtin_amdgcn_mfma_f32_16x16x32_bf16((a),(b),(c),0,0,0)

// ============================================================================
// prep: build transposed/padded bf16 weights in workspace
// ============================================================================
__global__ __launch_bounds__(256) void prep_kernel(
    const float* __restrict__ W0, const float* __restrict__ W1r, const float* __restrict__ W1i,
    const float* __restrict__ W2r, const float* __restrict__ W2i,
    const float* __restrict__ Gw, const float* __restrict__ Ew,
    const float* __restrict__ A1, const float* __restrict__ A2, const float* __restrict__ A3,
    const float* __restrict__ B1, const float* __restrict__ B2, const float* __restrict__ B3,
    const float* __restrict__ O0, const float* __restrict__ O1, const float* __restrict__ O2,
    const float* __restrict__ P0w, const float* __restrict__ P1w, const float* __restrict__ P2w,
    us_t* __restrict__ wb)
{
    int idx = blockIdx.x * 256 + threadIdx.x;
    if (idx >= W_TOTAL) return;
    float v;
    if (idx < WO_W1P) {                        // W0T [160][352], pad k 336->352
        int r = idx, n = r / 352, k = r % 352;
        v = (k < 336) ? W0[n * 336 + k] : 0.f;
    } else if (idx < WO_W1M) {                 // [W1r | -W1i]  [48][288]
        int r = idx - WO_W1P, n = r / 288, k = r % 288;
        v = (k < 144) ? W1r[n * 144 + k] : -W1i[n * 144 + (k - 144)];
    } else if (idx < WO_W2P) {                 // [W1i | W1r]
        int r = idx - WO_W1M, n = r / 288, k = r % 288;
        v = (k < 144) ? W1i[n * 144 + k] : W1r[n * 144 + (k - 144)];
    } else if (idx < WO_W2M) {                 // [W2r | -W2i]  [16][96]
        int r = idx - WO_W2P, n = r / 96, k = r % 96;
        v = (k < 48) ? W2r[n * 48 + k] : -W2i[n * 48 + (k - 48)];
    } else if (idx < WO_GW) {                  // [W2i | W2r]
        int r = idx - WO_W2M, n = r / 96, k = r % 96;
        v = (k < 48) ? W2i[n * 48 + k] : W2r[n * 48 + (k - 48)];
    } else if (idx < WO_EW) {                  // GwT [224][128]
        int r = idx - WO_GW, n = r / 128, k = r % 128;
        v = Gw[k * 224 + n];
    } else if (idx < WO_A1) {                  // EwT [112][128]
        int r = idx - WO_EW, n = r / 128, k = r % 128;
        v = Ew[k * 112 + n];
    } else if (idx < WO_A2) {                  // A1T [128][192]
        int r = idx - WO_A1, n = r / 192, k = r % 192;
        v = A1[k * 128 + n];
    } else if (idx < WO_A3) {                  // A2T [128][128]
        int r = idx - WO_A2, n = r / 128, k = r % 128;
        v = A2[k * 128 + n];
    } else if (idx < WO_B1) {                  // A3T
        int r = idx - WO_A3, n = r / 128, k = r % 128;
        v = A3[k * 128 + n];
    } else if (idx < WO_B2) {                  // B1T [128][256]
        int r = idx - WO_B1, n = r / 256, k = r % 256;
        v = B1[k * 128 + n];
    } else if (idx < WO_B3) {                  // B2T
        int r = idx - WO_B2, n = r / 128, k = r % 128;
        v = B2[k * 128 + n];
    } else if (idx < WO_O0) {                  // B3T
        int r = idx - WO_B3, n = r / 128, k = r % 128;
        v = B3[k * 128 + n];
    } else if (idx < WO_O1) {                  // O0 [64][128] already N-major
        v = O0[idx - WO_O0];
    } else if (idx < WO_O2) {
        v = O1[idx - WO_O1];
    } else if (idx < WO_P0T) {
        v = O2[idx - WO_O2];
    } else if (idx < WO_P1T) {                 // P0 [64][64] N-major
        v = P0w[idx - WO_P0T];
    } else if (idx < WO_P2T) {                 // P1 [32][32] N-major
        v = P1w[idx - WO_P1T];
    } else {                                   // P2 [16][32], k>=16 zero
        int r = idx - WO_P2T, n = r / 32, k = r % 32;
        v = (k < 16) ? P2w[n * 16 + k] : 0.f;
    }
    wb[idx] = f2b(v);
}

// ============================================================================
// kcopy: out_lat[row] = latents[row] for INACTIVE rows only (binary search in
//        sorted active_edges). Active rows are written by k2's scatter.
// ============================================================================
__global__ __launch_bounds__(256) void kcopy_kernel(
    const float* __restrict__ latents, const int* __restrict__ act,
    float* __restrict__ out_lat)
{
    int idx = blockIdx.x * 256 + threadIdx.x;   // E_TOT * 16
    if (idx >= E_TOT * 16) return;
    int row = idx >> 4, part = idx & 15;
    int lo = 0, hi = E_ACT;
    while (lo < hi) {
        int mid = (lo + hi) >> 1;
        if (act[mid] < row) lo = mid + 1; else hi = mid;
    }
    bool active = (lo < E_ACT) && (act[lo] == row);
    if (!active) {
        const float4* src = (const float4*)&latents[(size_t)row * 128 + part * 8];
        float4* dst = (float4*)&out_lat[(size_t)row * 128 + part * 8];
        dst[0] = src[0];
        dst[1] = src[1];
    }
}

// ---- latent A-fragment fetch (global -> regs, bf16) ----
__device__ __forceinline__ void lat_fetch_a(const float* __restrict__ latents,
                                            const int* __restrict__ aes_l,
                                            int lane, bf16x8 a[4])
{
    const int r = lane & 15, g = lane >> 4;
    const float* lp = latents + (size_t)aes_l[r] * 128 + g * 8;
    #pragma unroll
    for (int ks = 0; ks < 4; ++ks) {
        float4 v0 = *(const float4*)(lp + ks * 32);
        float4 v1 = *(const float4*)(lp + ks * 32 + 4);
        bf16x8 av;
        av[0] = (short)f2b(v0.x); av[1] = (short)f2b(v0.y);
        av[2] = (short)f2b(v0.z); av[3] = (short)f2b(v0.w);
        av[4] = (short)f2b(v1.x); av[5] = (short)f2b(v1.y);
        av[6] = (short)f2b(v1.z); av[7] = (short)f2b(v1.w);
        a[ks] = av;
    }
}

// ---- M=32 W0 tile fused with its Gw gate tile ----
__device__ __forceinline__ void gemmW0g32(
    const us_t* __restrict__ in0s, const us_t* __restrict__ wbase,
    const bf16x8 lA[4], const bf16x8 lB[4], const float* __restrict__ Gb,
    int nt, us_t* __restrict__ om0g, int lane)
{
    const int r = lane & 15, g = lane >> 4;
    f32x4 wa = {0.f,0.f,0.f,0.f}, wb = wa, ga = wa, gb = wa;
    const us_t* apA = in0s + r * 360 + g * 8;
    const us_t* apB = in0s + (16 + r) * 360 + g * 8;
    const us_t* wp  = wbase + WO_W0 + (size_t)(nt * 16 + r) * 352 + g * 8;
    #pragma unroll
    for (int ks = 0; ks < 11; ++ks) {
        bf16x8 b = *(const bf16x8*)(wp + ks * 32);
        wa = MFMA(*(const bf16x8*)(apA + ks * 32), b, wa);
        wb = MFMA(*(const bf16x8*)(apB + ks * 32), b, wb);
    }
    const us_t* gp = wbase + WO_GW + (size_t)(nt * 16 + r) * 128 + g * 8;
    #pragma unroll
    for (int ks = 0; ks < 4; ++ks) {
        bf16x8 b = *(const bf16x8*)(gp + ks * 32);
        ga = MFMA(lA[ks], b, ga);
        gb = MFMA(lB[ks], b, gb);
    }
    float bi = Gb[nt * 16 + r];
    #pragma unroll
    for (int i = 0; i < 4; ++i) {
        int eA = g * 4 + i, eB = 16 + g * 4 + i;
        om0g[eA * 162 + nt * 16 + r] = f2b(wa[i] * (ga[i] + bi));
        om0g[eB * 162 + nt * 16 + r] = f2b(wb[i] * (gb[i] + bi));
    }
}

// ---- M=32 W1 tile j (P and M) fused with gate tile ----
__device__ __forceinline__ void gemmW1g32(
    const us_t* __restrict__ cact1, const us_t* __restrict__ wbase,
    const bf16x8 lA[4], const bf16x8 lB[4], const float* __restrict__ Gb,
    int j, us_t* __restrict__ cp1g, us_t* __restrict__ cn1g, int lane)
{
    const int r = lane & 15, g = lane >> 4;
    f32x4 pa = {0.f,0.f,0.f,0.f}, pb = pa, ma = pa, mb = pa, ga = pa, gb = pa;
    const us_t* apA = cact1 + r * 296 + g * 8;
    const us_t* apB = cact1 + (16 + r) * 296 + g * 8;
    const us_t* wpP = wbase + WO_W1P + (size_t)(j * 16 + r) * 288 + g * 8;
    const us_t* wpM = wbase + WO_W1M + (size_t)(j * 16 + r) * 288 + g * 8;
    #pragma unroll
    for (int ks = 0; ks < 9; ++ks) {
        bf16x8 aA = *(const bf16x8*)(apA + ks * 32);
        bf16x8 aB = *(const bf16x8*)(apB + ks * 32);
        bf16x8 bP = *(const bf16x8*)(wpP + ks * 32);
        bf16x8 bM = *(const bf16x8*)(wpM + ks * 32);
        pa = MFMA(aA, bP, pa); pb = MFMA(aB, bP, pb);
        ma = MFMA(aA, bM, ma); mb = MFMA(aB, bM, mb);
    }
    const us_t* gp = wbase + WO_GW + (size_t)(160 + j * 16 + r) * 128 + g * 8;
    #pragma unroll
    for (int ks = 0; ks < 4; ++ks) {
        bf16x8 b = *(const bf16x8*)(gp + ks * 32);
        ga = MFMA(lA[ks], b, ga);
        gb = MFMA(lB[ks], b, gb);
    }
    float bi = Gb[160 + j * 16 + r];
    #pragma unroll
    for (int i = 0; i < 4; ++i) {
        int eA = g * 4 + i, eB = 16 + g * 4 + i;
        float gA = ga[i] + bi, gB = gb[i] + bi;
        cp1g[eA * 50 + j * 16 + r] = f2b(pa[i] * gA);
        cn1g[eA * 50 + j * 16 + r] = f2b(ma[i] * gA);
        cp1g[eB * 50 + j * 16 + r] = f2b(pb[i] * gB);
        cn1g[eB * 50 + j * 16 + r] = f2b(mb[i] * gB);
    }
}

// ---- M=32 W2 (P and M) fused with gate tile ----
__device__ __forceinline__ void gemmW2g32(
    const us_t* __restrict__ cact2, const us_t* __restrict__ wbase,
    const bf16x8 lA[4], const bf16x8 lB[4], const float* __restrict__ Gb,
    us_t* __restrict__ cp2g, us_t* __restrict__ cn2g, int lane)
{
    const int r = lane & 15, g = lane >> 4;
    f32x4 pa = {0.f,0.f,0.f,0.f}, pb = pa, ma = pa, mb = pa, ga = pa, gb = pa;
    const us_t* apA = cact2 + r * 104 + g * 8;
    const us_t* apB = cact2 + (16 + r) * 104 + g * 8;
    const us_t* wpP = wbase + WO_W2P + (size_t)r * 96 + g * 8;
    const us_t* wpM = wbase + WO_W2M + (size_t)r * 96 + g * 8;
    #pragma unroll
    for (int ks = 0; ks < 3; ++ks) {
        bf16x8 aA = *(const bf16x8*)(apA + ks * 32);
        bf16x8 aB = *(const bf16x8*)(apB + ks * 32);
        bf16x8 bP = *(const bf16x8*)(wpP + ks * 32);
        bf16x8 bM = *(const bf16x8*)(wpM + ks * 32);
        pa = MFMA(aA, bP, pa); pb = MFMA(aB, bP, pb);
        ma = MFMA(aA, bM, ma); mb = MFMA(aB, bM, mb);
    }
    const us_t* gp = wbase + WO_GW + (size_t)(208 + r) * 128 + g * 8;
    #pragma unroll
    for (int ks = 0; ks < 4; ++ks) {
        bf16x8 b = *(const bf16x8*)(gp + ks * 32);
        ga = MFMA(lA[ks], b, ga);
        gb = MFMA(lB[ks], b, gb);
    }
    float bi = Gb[208 + r];
    #pragma unroll
    for (int i = 0; i < 4; ++i) {
        int eA = g * 4 + i, eB = 16 + g * 4 + i;
        float gA = ga[i] + bi, gB = gb[i] + bi;
        cp2g[eA * 18 + r] = f2b(pa[i] * gA);
        cn2g[eA * 18 + r] = f2b(ma[i] * gA);
        cp2g[eB * 18 + r] = f2b(pb[i] * gB);
        cn2g[eB * 18 + r] = f2b(mb[i] * gB);
    }
}

// ---- M=32 Ew tile -> wl ----
__device__ __forceinline__ void lat_gemmE32(
    const bf16x8 lA[4], const bf16x8 lB[4],
    const us_t* __restrict__ wgt, const float* __restrict__ bias,
    int nt, us_t* __restrict__ wl, int lane)
{
    const int r = lane & 15, g = lane >> 4;
    f32x4 aA = {0.f,0.f,0.f,0.f}, aB = aA;
    const us_t* wp = wgt + (size_t)(nt * 16 + r) * 128 + g * 8;
    #pragma unroll
    for (int ks = 0; ks < 4; ++ks) {
        bf16x8 b = *(const bf16x8*)(wp + ks * 32);
        aA = MFMA(lA[ks], b, aA);
        aB = MFMA(lB[ks], b, aB);
    }
    float bi = bias[nt * 16 + r];
    #pragma unroll
    for (int i = 0; i < 4; ++i) {
        int eA = g * 4 + i, eB = 16 + g * 4 + i;
        wl[eA * 120 + nt * 16 + r] = f2b(aA[i] + bi);
        wl[eB * 120 + nt * 16 + r] = f2b(aB[i] + bi);
    }
}

// ---- M=32 P-projection ----
template<int KS>
__device__ __forceinline__ void pgemm32(const us_t* __restrict__ actbase, int as,
                                        const us_t* __restrict__ wgt, int kp, int lane,
                                        f32x4& accA, f32x4& accB)
{
    const int r = lane & 15, g = lane >> 4;
    const us_t* apA = actbase + r * as + g * 8;
    const us_t* apB = actbase + (16 + r) * as + g * 8;
    const us_t* wp = wgt + (size_t)r * kp + g * 8;
    #pragma unroll
    for (int ks = 0; ks < KS; ++ks) {
        bf16x8 b = *(const bf16x8*)(wp + ks * 32);
        accA = MFMA(*(const bf16x8*)(apA + ks * 32), b, accA);
        accB = MFMA(*(const bf16x8*)(apB + ks * 32), b, accB);
    }
}

// ============================================================================
// K1 (R10 winner, unchanged): 32 edges / 256 threads, M=32 MFMA tiles.
// ============================================================================
__global__ __launch_bounds__(256, 2) void k1_kernel(
    const float* __restrict__ latents,
    const float* __restrict__ node_features,
    const float* __restrict__ edge_features,
    const float* __restrict__ wD1,
    const float* __restrict__ wD2,
    const float* __restrict__ Gb,  const float* __restrict__ Eb,
    const float* __restrict__ P0b,
    const int* __restrict__ edge_index, const int* __restrict__ active_edges,
    const us_t* __restrict__ wbase,
    us_t* __restrict__ ne_ws, us_t* __restrict__ scal_ws)
{
    __shared__ __align__(16) char smem[80640];
    us_t* in0s  = (us_t*)(smem);            // [32][360] K=352 (W0)
    us_t* cact1 = (us_t*)(smem + 23040);    // [32][296] [ip1|im1] K=288
    us_t* cact2 = (us_t*)(smem + 41984);    // [32][104] [r24|r20] K=96
    float* D1l  = (float*)(smem + 48640);   // [32][12]
    float* D2l  = (float*)(smem + 50176);   // [32][28]
    int*   aes  = (int*)(smem + 53760);     // [32]
    us_t* om0g  = (us_t*)(smem + 53888);    // [32][162] gated o_m0 (160)
    us_t* cp1g  = (us_t*)(smem + 64256);    // [32][50]
    us_t* cn1g  = (us_t*)(smem + 67456);    // [32][50]
    us_t* cp2g  = (us_t*)(smem + 70656);    // [32][18]
    us_t* cn2g  = (us_t*)(smem + 71808);    // [32][18]
    us_t* wl    = (us_t*)(smem + 72960);    // [32][120] w (112)
    us_t* z0l   = (us_t*)(smem);            // [32] stride 72 (K=64)
    us_t* z1l   = (us_t*)(smem + 4608);     // [32] stride 104 (m*32+u, K=32)
    us_t* z2l   = (us_t*)(smem + 11264);    // [32] stride 168 (m*32+u, pad 0)

    const int t  = threadIdx.x;
    const int e0 = blockIdx.x * 32;

    // ---------------- Phase A: register gather + rotate (2 passes x 16 edges) --
    #pragma unroll
    for (int ep = 0; ep < 2; ++ep) {
        const int e = (t >> 4) + 16 * ep, l = t & 15;
        const int eg = e0 + e;
        const int ae = active_edges[eg];
        const int ec = edge_index[ae];
        const int en = edge_index[E_TOT + ae];
        if (l == 0) aes[e] = ae;

        float v1  = (l < 9) ? wD1[(size_t)eg * 9 + l] : 0.f;
        float v2a = wD2[(size_t)eg * 25 + l];
        float v2b = (l < 9) ? wD2[(size_t)eg * 25 + 16 + l] : 0.f;
        if (l < 9) D1l[e * 12 + l] = v1;
        D2l[e * 28 + l] = v2a;
        if (l < 9) D2l[e * 28 + 16 + l] = v2b;

        float d1[9], d2[25];
        #pragma unroll
        for (int i = 0; i < 9; ++i)  d1[i] = __shfl(v1, i, 16);
        #pragma unroll
        for (int i = 0; i < 16; ++i) d2[i] = __shfl(v2a, i, 16);
        #pragma unroll
        for (int i = 0; i < 9; ++i)  d2[16 + i] = __shfl(v2b, i, 16);

        const float* pc = node_features + (size_t)ec * DIR;
        const float* pe = edge_features + (size_t)eg * DIR;
        const float* pn = node_features + (size_t)en * DIR;
        us_t* in0 = in0s + e * 360;
        us_t* c1  = cact1 + e * 296;
        us_t* c2  = cact2 + e * 104;

        #pragma unroll
        for (int j = 0; j < 4; ++j) {
            int i = l + 16 * j;
            in0[i]       = f2b(pc[i]);
            in0[64 + i]  = f2b(pe[i]);
            in0[128 + i] = f2b(pn[i]);
        }
        in0[336 + l] = 0;   // zero K-pad 336..351

        #pragma unroll
        for (int jj = 0; jj < 6; ++jj) {
            int u = l + 16 * jj;
            int uu = u & 31;
            const float* sp = (u < 32 ? pc : (u < 64 ? pe : pn)) + 64 + uu * 3;
            float x0 = sp[0], x1 = sp[1], x2 = sp[2];
            float r0 = d1[0] * x0 + d1[1] * x1 + d1[2] * x2;
            float r1 = d1[3] * x0 + d1[4] * x1 + d1[5] * x2;
            float r2 = d1[6] * x0 + d1[7] * x1 + d1[8] * x2;
            c1[144 + u]  = f2b(r0);   // im1 part 1
            in0[192 + u] = f2b(r1);
            c1[u]        = f2b(r2);   // ip1 part 1
        }
        #pragma unroll
        for (int jj = 0; jj < 3; ++jj) {
            int u = l + 16 * jj;
            int uu = u & 15;
            const float* sp = (u < 16 ? pc : (u < 32 ? pe : pn)) + 160 + uu * 5;
            float x0 = sp[0], x1 = sp[1], x2 = sp[2], x3 = sp[3], x4 = sp[4];
            float r[5];
            #pragma unroll
            for (int i = 0; i < 5; ++i)
                r[i] = d2[i * 5 + 0] * x0 + d2[i * 5 + 1] * x1 + d2[i * 5 + 2] * x2
                     + d2[i * 5 + 3] * x3 + d2[i * 5 + 4] * x4;
            c2[48 + u]   = f2b(r[0]);  // r20
            c1[240 + u]  = f2b(r[1]);  // im1 part 2
            in0[288 + u] = f2b(r[2]);
            c1[96 + u]   = f2b(r[3]);  // ip1 part 2
            c2[u]        = f2b(r[4]);  // r24
        }
    }
    __syncthreads();

    // ---------------- Phase B: gate-fused M=32 MFMA GEMMs (4 waves) -----------
    {
        const int lane = t & 63, w = t >> 6;
        bf16x8 lA[4], lB[4];
        lat_fetch_a(latents, aes, lane, lA);
        lat_fetch_a(latents, aes + 16, lane, lB);
        if (w == 0) {
            gemmW0g32(in0s, wbase, lA, lB, Gb, 0, om0g, lane);
            gemmW0g32(in0s, wbase, lA, lB, Gb, 1, om0g, lane);
            gemmW0g32(in0s, wbase, lA, lB, Gb, 2, om0g, lane);
            gemmW1g32(cact1, wbase, lA, lB, Gb, 0, cp1g, cn1g, lane);
        } else if (w == 1) {
            gemmW0g32(in0s, wbase, lA, lB, Gb, 3, om0g, lane);
            gemmW0g32(in0s, wbase, lA, lB, Gb, 4, om0g, lane);
            gemmW0g32(in0s, wbase, lA, lB, Gb, 5, om0g, lane);
            gemmW1g32(cact1, wbase, lA, lB, Gb, 1, cp1g, cn1g, lane);
        } else if (w == 2) {
            gemmW0g32(in0s, wbase, lA, lB, Gb, 6, om0g, lane);
            gemmW0g32(in0s, wbase, lA, lB, Gb, 7, om0g, lane);
            gemmW0g32(in0s, wbase, lA, lB, Gb, 8, om0g, lane);
            gemmW1g32(cact1, wbase, lA, lB, Gb, 2, cp1g, cn1g, lane);
        } else {
            gemmW0g32(in0s, wbase, lA, lB, Gb, 9, om0g, lane);
            gemmW2g32(cact2, wbase, lA, lB, Gb, cp2g, cn2g, lane);
            #pragma unroll
            for (int nt = 0; nt < 7; ++nt)
                lat_gemmE32(lA, lB, wbase + WO_EW, Eb, nt, wl, lane);
        }
    }
    __syncthreads();

    // ---------------- Phase C: y-build + D^T + silu -> z (2 passes) -----------
    #pragma unroll
    for (int ep = 0; ep < 2; ++ep) {
        const int e = (t >> 4) + 16 * ep, l = t & 15;
        const float* D1e = D1l + e * 12;
        const float* D2e = D2l + e * 28;
        #pragma unroll
        for (int uu = 0; uu < 2; ++uu) {
            int u = l + uu * 16;
            float j0 = b2f(cn1g[e * 50 + u]);
            float j1 = b2f(om0g[e * 162 + 112 + u]);
            float j2 = b2f(cp1g[e * 50 + u]);
            float gate = sigm(b2f(om0g[e * 162 + 64 + u]));
            #pragma unroll
            for (int i = 0; i < 3; ++i) {
                float yr = D1e[0 * 3 + i] * j0 + D1e[1 * 3 + i] * j1 + D1e[2 * 3 + i] * j2;
                z1l[e * 104 + i * 32 + u] = f2b(yr * gate);   // m-major
            }
        }
        {
            int u = l;
            float j0 = b2f(cn2g[e * 18 + u]);
            float j1 = b2f(cn1g[e * 50 + 32 + u]);
            float j2 = b2f(om0g[e * 162 + 144 + u]);
            float j3 = b2f(cp1g[e * 50 + 32 + u]);
            float j4 = b2f(cp2g[e * 18 + u]);
            float gate = sigm(b2f(om0g[e * 162 + 96 + u]));
            #pragma unroll
            for (int i = 0; i < 5; ++i) {
                float yr = D2e[0 * 5 + i] * j0 + D2e[1 * 5 + i] * j1 + D2e[2 * 5 + i] * j2
                         + D2e[3 * 5 + i] * j3 + D2e[4 * 5 + i] * j4;
                z2l[e * 168 + i * 32 + u] = f2b(yr * gate);   // m-major
                z2l[e * 168 + i * 32 + 16 + u] = 0;           // zero K 16..31
            }
        }
        #pragma unroll
        for (int ii = 0; ii < 4; ++ii) {
            int c = l + 16 * ii;
            float v = b2f(om0g[e * 162 + c]);
            z0l[e * 72 + c] = f2b(v * sigm(v));               // z0 = silu
        }
    }
    __syncthreads();

    // ---------------- Phase D: M=32 MFMA P-projections + w-scale --------------
    {
        const int lane = t & 63, w = t >> 6;
        const int r = lane & 15, g = lane >> 4;
        const float sc1 = 0.17677669529663687f;
        if (w < 2) {
            #pragma unroll
            for (int jj = 0; jj < 2; ++jj) {
                int nt = 2 * w + jj;
                f32x4 aA = {0.f,0.f,0.f,0.f}, aB = aA;
                pgemm32<2>(z0l, 72, wbase + WO_P0T + nt * 16 * 64, 64, lane, aA, aB);
                int n = nt * 16 + r;
                float bi = P0b[n];
                #pragma unroll
                for (int i = 0; i < 4; ++i) {
                    int eA = g * 4 + i, eB = 16 + g * 4 + i;
                    float zA = aA[i] * 0.125f + bi;
                    float zB = aB[i] * 0.125f + bi;
                    scal_ws[(size_t)(e0 + eA) * 64 + n] = f2b(zA);
                    scal_ws[(size_t)(e0 + eB) * 64 + n] = f2b(zB);
                    ne_ws[(size_t)(e0 + eA) * 240 + n] = f2b(zA * b2f(wl[eA * 120 + n]));
                    ne_ws[(size_t)(e0 + eB) * 240 + n] = f2b(zB * b2f(wl[eB * 120 + n]));
                }
            }
        } else if (w == 2) {
            #pragma unroll
            for (int m = 0; m < 3; ++m) {
                #pragma unroll
                for (int nt = 0; nt < 2; ++nt) {
                    f32x4 aA = {0.f,0.f,0.f,0.f}, aB = aA;
                    pgemm32<1>(z1l + m * 32, 104, wbase + WO_P1T + nt * 16 * 32, 32,
                               lane, aA, aB);
                    int u = nt * 16 + r;
                    #pragma unroll
                    for (int i = 0; i < 4; ++i) {
                        int eA = g * 4 + i, eB = 16 + g * 4 + i;
                        ne_ws[(size_t)(e0 + eA) * 240 + 64 + u * 3 + m] =
                            f2b(aA[i] * sc1 * b2f(wl[eA * 120 + 64 + u]));
                        ne_ws[(size_t)(e0 + eB) * 240 + 64 + u * 3 + m] =
                            f2b(aB[i] * sc1 * b2f(wl[eB * 120 + 64 + u]));
                    }
                }
            }
        } else if (w == 3) {
            #pragma unroll
            for (int m = 0; m < 5; ++m) {
                f32x4 aA = {0.f,0.f,0.f,0.f}, aB = aA;
                pgemm32<1>(z2l + m * 32, 168, wbase + WO_P2T, 32, lane, aA, aB);
                int u = r;
                #pragma unroll
                for (int i = 0; i < 4; ++i) {
                    int eA = g * 4 + i, eB = 16 + g * 4 + i;
                    ne_ws[(size_t)(e0 + eA) * 240 + 160 + u * 5 + m] =
                        f2b(aA[i] * 0.25f * b2f(wl[eA * 120 + 96 + u]));
                    ne_ws[(size_t)(e0 + eB) * 240 + 160 + u * 5 + m] =
                        f2b(aB[i] * 0.25f * b2f(wl[eB * 120 + 96 + u]));
                }
            }
        }
    }
}

// ============================================================================
// K2: M=64 (64 edges / 256 threads). Each weight fragment feeds 4 MFMAs.
//     LDS 78336B -> 2 blocks/CU.
// ============================================================================
template<int KS, bool SILU>
__device__ __forceinline__ void mlayer64(
    const us_t* __restrict__ actA, const us_t* __restrict__ actB, int split, int as,
    const us_t* __restrict__ wgt, int kp, const float* __restrict__ bias,
    us_t* __restrict__ out, int os, int lane, int w)
{
    const int r = lane & 15, g = lane >> 4;
    const int n0 = 2 * w * 16, n1 = n0 + 16;
    f32x4 a0e0 = {0.f,0.f,0.f,0.f}, a0e1 = a0e0, a0e2 = a0e0, a0e3 = a0e0;
    f32x4 a1e0 = a0e0, a1e1 = a0e0, a1e2 = a0e0, a1e3 = a0e0;
    const us_t* wp0 = wgt + (size_t)(n0 + r) * kp + g * 8;
    const us_t* wp1 = wgt + (size_t)(n1 + r) * kp + g * 8;
    #pragma unroll
    for (int ks = 0; ks < KS; ++ks) {
        const us_t* ab = (ks < split) ? (actA + ks * 32) : (actB + (ks - split) * 32);
        bf16x8 b0 = *(const bf16x8*)(wp0 + ks * 32);
        bf16x8 b1 = *(const bf16x8*)(wp1 + ks * 32);
        bf16x8 f0 = *(const bf16x8*)(ab + (r)      * as + g * 8);
        bf16x8 f1 = *(const bf16x8*)(ab + (16 + r) * as + g * 8);
        bf16x8 f2 = *(const bf16x8*)(ab + (32 + r) * as + g * 8);
        bf16x8 f3 = *(const bf16x8*)(ab + (48 + r) * as + g * 8);
        a0e0 = MFMA(f0, b0, a0e0); a1e0 = MFMA(f0, b1, a1e0);
        a0e1 = MFMA(f1, b0, a0e1); a1e1 = MFMA(f1, b1, a1e1);
        a0e2 = MFMA(f2, b0, a0e2); a1e2 = MFMA(f2, b1, a1e2);
        a0e3 = MFMA(f3, b0, a0e3); a1e3 = MFMA(f3, b1, a1e3);
    }
    float bi0 = bias[n0 + r], bi1 = bias[n1 + r];
    f32x4 A0[4] = {a0e0, a0e1, a0e2, a0e3};
    f32x4 A1[4] = {a1e0, a1e1, a1e2, a1e3};
    #pragma unroll
    for (int eg = 0; eg < 4; ++eg) {
        #pragma unroll
        for (int i = 0; i < 4; ++i) {
            int e = eg * 16 + g * 4 + i;
            float v;
            v = A0[eg][i] + bi0; if (SILU) v *= sigm(v); out[e * os + n0 + r] = f2b(v);
            v = A1[eg][i] + bi1; if (SILU) v *= sigm(v); out[e * os + n1 + r] = f2b(v);
        }
    }
}

__global__ __launch_bounds__(256, 2) void k2_kernel(
    const float* __restrict__ latents, const float* __restrict__ cutoff,
    const float* __restrict__ one_hot,
    const float* __restrict__ ln_g, const float* __restrict__ ln_b,
    const float* __restrict__ A1b, const float* __restrict__ A2b, const float* __restrict__ A3b,
    const float* __restrict__ B1b, const float* __restrict__ B2b, const float* __restrict__ B3b,
    const int* __restrict__ active_edges,
    const us_t* __restrict__ wbase,
    const us_t* __restrict__ scal_ws, us_t* __restrict__ ohw_ws,
    float* __restrict__ out_lat)
{
    __shared__ __align__(16) char smem[78336];
    us_t* x_lds = (us_t*)(smem);           // [64][200] (192 used)
    us_t* h_a   = (us_t*)(smem + 25600);   // [64][136]
    us_t* h_b   = (us_t*)(smem + 43008);   // [64][136]
    us_t* ohl   = (us_t*)(smem + 60416);   // [64][136]
    int*  aes_l = (int*)(smem + 77824);    // [64]
    float* cut_l= (float*)(smem + 78080);  // [64]

    const int t  = threadIdx.x;
    const int e0 = blockIdx.x * 64;
    const int lane = t & 63, w = t >> 6;

    // LN from latents (4 lanes/edge) + aes/cut staging
    {
        int ee = t >> 2, l4 = t & 3;
        int ae = active_edges[e0 + ee];
        if (l4 == 0) { aes_l[ee] = ae; cut_l[ee] = cutoff[ae]; }
        const float* lp = latents + (size_t)ae * 128 + l4 * 32;
        float xs[32];
        #pragma unroll
        for (int q = 0; q < 8; ++q) {
            float4 v = *(const float4*)(lp + q * 4);
            xs[q * 4 + 0] = v.x; xs[q * 4 + 1] = v.y;
            xs[q * 4 + 2] = v.z; xs[q * 4 + 3] = v.w;
        }
        float s1 = 0.f, s2 = 0.f;
        #pragma unroll
        for (int i = 0; i < 32; ++i) { s1 += xs[i]; s2 += xs[i] * xs[i]; }
        #pragma unroll
        for (int off = 1; off < 4; off <<= 1) {
            s1 += __shfl_xor(s1, off, 4);
            s2 += __shfl_xor(s2, off, 4);
        }
        float mu  = s1 * (1.f / 128.f);
        float var = s2 * (1.f / 128.f) - mu * mu;
        float rstd = rsqrtf(var + 1e-5f);
        #pragma unroll
        for (int i = 0; i < 32; ++i) {
            int li = l4 * 32 + i;
            x_lds[ee * 200 + li] = f2b((xs[i] - mu) * rstd * ln_g[li] + ln_b[li]);
        }
    }
    // scalars -> x[128:192]
    for (int idx = t; idx < 64 * 16; idx += 256) {
        int ee = idx >> 4, j = idx & 15;
        *(ushort4*)&x_lds[ee * 200 + 128 + j * 4] =
            *(const ushort4*)&scal_ws[(size_t)(e0 + ee) * 64 + j * 4];
    }
    // one-hot -> ohl
    for (int idx = t; idx < 64 * 32; idx += 256) {
        int ee = idx >> 5, j = idx & 31;
        float4 ov = *(const float4*)&one_hot[(size_t)(e0 + ee) * 128 + j * 4];
        ushort4 s; s.x = f2b(ov.x); s.y = f2b(ov.y); s.z = f2b(ov.z); s.w = f2b(ov.w);
        *(ushort4*)&ohl[ee * 136 + j * 4] = s;
    }
    __syncthreads();

    mlayer64<6, true>(x_lds, x_lds, 6, 200, wbase + WO_A1, 192, A1b, h_a, 136, lane, w);
    __syncthreads();
    mlayer64<4, true>(h_a, h_a, 4, 136, wbase + WO_A2, 128, A2b, h_b, 136, lane, w);
    __syncthreads();
    mlayer64<4, false>(h_b, h_b, 4, 136, wbase + WO_A3, 128, A3b, h_a, 136, lane, w);
    __syncthreads();
    mlayer64<8, true>(h_a, ohl, 4, 136, wbase + WO_B1, 256, B1b, h_b, 136, lane, w);
    __syncthreads();
    mlayer64<4, true>(h_b, h_b, 4, 136, wbase + WO_B2, 128, B2b, h_a, 136, lane, w);
    __syncthreads();
    // B3 fused with latent scatter (no LDS staging)
    {
        const int r = lane & 15, g = lane >> 4;
        const int n0 = 2 * w * 16, n1 = n0 + 16;
        f32x4 a0e0 = {0.f,0.f,0.f,0.f}, a0e1 = a0e0, a0e2 = a0e0, a0e3 = a0e0;
        f32x4 a1e0 = a0e0, a1e1 = a0e0, a1e2 = a0e0, a1e3 = a0e0;
        const us_t* wp0 = wbase + WO_B3 + (size_t)(n0 + r) * 128 + g * 8;
        const us_t* wp1 = wbase + WO_B3 + (size_t)(n1 + r) * 128 + g * 8;
        #pragma unroll
        for (int ks = 0; ks < 4; ++ks) {
            bf16x8 b0 = *(const bf16x8*)(wp0 + ks * 32);
            bf16x8 b1 = *(const bf16x8*)(wp1 + ks * 32);
            bf16x8 f0 = *(const bf16x8*)(h_a + ks * 32 + (r)      * 136 + g * 8);
            bf16x8 f1 = *(const bf16x8*)(h_a + ks * 32 + (16 + r) * 136 + g * 8);
            bf16x8 f2 = *(const bf16x8*)(h_a + ks * 32 + (32 + r) * 136 + g * 8);
            bf16x8 f3 = *(const bf16x8*)(h_a + ks * 32 + (48 + r) * 136 + g * 8);
            a0e0 = MFMA(f0, b0, a0e0); a1e0 = MFMA(f0, b1, a1e0);
            a0e1 = MFMA(f1, b0, a0e1); a1e1 = MFMA(f1, b1, a1e1);
            a0e2 = MFMA(f2, b0, a0e2); a1e2 = MFMA(f2, b1, a1e2);
            a0e3 = MFMA(f3, b0, a0e3); a1e3 = MFMA(f3, b1, a1e3);
        }
        float bi0 = B3b[n0 + r], bi1 = B3b[n1 + r];
        f32x4 A0[4] = {a0e0, a0e1, a0e2, a0e3};
        f32x4 A1[4] = {a1e0, a1e1, a1e2, a1e3};
        #pragma unroll
        for (int eg = 0; eg < 4; ++eg) {
            #pragma unroll
            for (int i = 0; i < 4; ++i) {
                int e = eg * 16 + g * 4 + i;
                int ae = aes_l[e];
                float c = C_NEW * cut_l[e];
                float* o = out_lat + (size_t)ae * 128;
                const float* lt = latents + (size_t)ae * 128;
                o[n0 + r] = c * (A0[eg][i] + bi0) + C_OLD * lt[n0 + r];
                o[n1 + r] = c * (A1[eg][i] + bi1) + C_OLD * lt[n1 + r];
            }
        }
    }

    // O-projections (reads ohl only): tiles {w, w+4 (if w<3)}
    {
        const int r = lane & 15, g = lane >> 4;
        const int cnt = (w == 3) ? 1 : 2;
        #pragma unroll
        for (int ii = 0; ii < 2; ++ii) {
            if (ii >= cnt) break;
            int nt = (ii == 0) ? w : w + 4;
            const us_t* wb2 = (nt < 4) ? (wbase + WO_O0 + (size_t)nt * 16 * 128)
                            : (nt < 6) ? (wbase + WO_O1 + (size_t)(nt - 4) * 16 * 128)
                                       : (wbase + WO_O2);
            f32x4 c0 = {0.f,0.f,0.f,0.f}, c1 = c0, c2 = c0, c3 = c0;
            const us_t* wp = wb2 + (size_t)r * 128 + g * 8;
            #pragma unroll
            for (int ks = 0; ks < 4; ++ks) {
                bf16x8 b = *(const bf16x8*)(wp + ks * 32);
                bf16x8 f0 = *(const bf16x8*)(ohl + ks * 32 + (r)      * 136 + g * 8);
                bf16x8 f1 = *(const bf16x8*)(ohl + ks * 32 + (16 + r) * 136 + g * 8);
                bf16x8 f2 = *(const bf16x8*)(ohl + ks * 32 + (32 + r) * 136 + g * 8);
                bf16x8 f3 = *(const bf16x8*)(ohl + ks * 32 + (48 + r) * 136 + g * 8);
                c0 = MFMA(f0, b, c0); c1 = MFMA(f1, b, c1);
                c2 = MFMA(f2, b, c2); c3 = MFMA(f3, b, c3);
            }
            int n = nt * 16 + r;
            f32x4 C[4] = {c0, c1, c2, c3};
            #pragma unroll
            for (int eg = 0; eg < 4; ++eg) {
                #pragma unroll
                for (int i = 0; i < 4; ++i) {
                    int e = e0 + eg * 16 + g * 4 + i;
                    ohw_ws[(size_t)e * 112 + n] = f2b(C[eg][i]);
                }
            }
        }
    }
}

// ============================================================================
// K3: edge_out = (c_old*ef + c_new*ne) * (1 + s*oh), 4 elems/thread
// ============================================================================
__global__ __launch_bounds__(256) void kfin_kernel(
    const float* __restrict__ edge_features, const us_t* __restrict__ ne_ws,
    const us_t* __restrict__ ohw_ws, float* __restrict__ out_edge)
{
    int idx = blockIdx.x * 256 + threadIdx.x;   // over E_ACT*60 float4s
    if (idx >= E_ACT * 60) return;
    int e = idx / 60;
    int c0 = (idx - e * 60) * 4;
    float4 ef = *(const float4*)&edge_features[(size_t)e * 240 + c0];
    ushort4 nv = *(const ushort4*)&ne_ws[(size_t)e * 240 + c0];
    float nef[4] = {b2f(nv.x), b2f(nv.y), b2f(nv.z), b2f(nv.w)};
    float eff[4] = {ef.x, ef.y, ef.z, ef.w};
    float4 ov;
    float* op = &ov.x;
    #pragma unroll
    for (int j = 0; j < 4; ++j) {
        int c = c0 + j;
        int o;
        if (c < 64)       o = c;
        else if (c < 160) o = 64 + (c - 64) / 3;
        else              o = 96 + (c - 160) / 5;
        float ohv = b2f(ohw_ws[(size_t)e * 112 + o]);
        op[j] = (C_OLD * eff[j] + C_NEW * nef[j]) * (1.f + S_OH * ohv);
    }
    *(float4*)&out_edge[(size_t)e * 240 + c0] = ov;
}

// ============================================================================
extern "C" void kernel_launch(void* const* d_in, const int* in_sizes, int n_in,
                              void* d_out, int out_size, void* d_ws, size_t ws_size,
                              hipStream_t stream)
{
    const float* latents  = (const float*)d_in[0];
    const float* node_f   = (const float*)d_in[1];
    const float* edge_f   = (const float*)d_in[2];
    const float* cutoff   = (const float*)d_in[3];
    const float* one_hot  = (const float*)d_in[4];
    const float* wD1      = (const float*)d_in[5];
    const float* wD2      = (const float*)d_in[6];
    const float* W0       = (const float*)d_in[7];
    const float* W1r      = (const float*)d_in[8];
    const float* W1i      = (const float*)d_in[9];
    const float* W2r      = (const float*)d_in[10];
    const float* W2i      = (const float*)d_in[11];
    const float* Gw       = (const float*)d_in[12];
    const float* Gb       = (const float*)d_in[13];
    const float* P0w      = (const float*)d_in[14];
    const float* P0b      = (const float*)d_in[15];
    const float* P1w      = (const float*)d_in[16];
    const float* P2w      = (const float*)d_in[17];
    const float* Ew       = (const float*)d_in[18];
    const float* Eb       = (const float*)d_in[19];
    const float* ln_g     = (const float*)d_in[20];
    const float* ln_b     = (const float*)d_in[21];
    const float* A1       = (const float*)d_in[22];
    const float* A1b      = (const float*)d_in[23];
    const float* A2       = (const float*)d_in[24];
    const float* A2b      = (const float*)d_in[25];
    const float* A3       = (const float*)d_in[26];
    const float* A3b      = (const float*)d_in[27];
    const float* B1       = (const float*)d_in[28];
    const float* B1b      = (const float*)d_in[29];
    const float* B2       = (const float*)d_in[30];
    const float* B2b      = (const float*)d_in[31];
    const float* B3       = (const float*)d_in[32];
    const float* B3b      = (const float*)d_in[33];
    const float* O0       = (const float*)d_in[34];
    const float* O1       = (const float*)d_in[35];
    const float* O2       = (const float*)d_in[36];
    const int* edge_index = (const int*)d_in[37];
    const int* act_e      = (const int*)d_in[38];

    float* out_edge = (float*)d_out;                      // E_ACT*240 f32
    float* out_lat  = out_edge + (size_t)E_ACT * DIR;     // E_TOT*128 f32

    // ws layout (bf16 elements): ne | ohw | scal | weights
    us_t* ne_ws   = (us_t*)d_ws;                           // E_ACT*240
    us_t* ohw_ws  = ne_ws + (size_t)E_ACT * DIR;           // E_ACT*112
    us_t* scal_ws = ohw_ws + (size_t)E_ACT * 112;          // E_ACT*64
    us_t* wbase   = scal_ws + (size_t)E_ACT * 64;          // W_TOTAL

    prep_kernel<<<dim3((W_TOTAL + 255) / 256), dim3(256), 0, stream>>>(
        W0, W1r, W1i, W2r, W2i, Gw, Ew, A1, A2, A3, B1, B2, B3,
        O0, O1, O2, P0w, P1w, P2w, wbase);

    k1_kernel<<<dim3(E_ACT / 32), dim3(256), 0, stream>>>(
        latents, node_f, edge_f, wD1, wD2, Gb, Eb, P0b,
        edge_index, act_e, wbase, ne_ws, scal_ws);

    kcopy_kernel<<<dim3((E_TOT * 16 + 255) / 256), dim3(256), 0, stream>>>(
        latents, act_e, out_lat);

    k2_kernel<<<dim3(E_ACT / 64), dim3(256), 0, stream>>>(
        latents, cutoff, one_hot, ln_g, ln_b,
        A1b, A2b, A3b, B1b, B2b, B3b,
        act_e, wbase, scal_ws, ohw_ws, out_lat);

    kfin_kernel<<<dim3((E_ACT * 60 + 255) / 256), dim3(256), 0, stream>>>(
        edge_f, ne_ws, ohw_ws, out_edge);
}

// Round 12
// 699.115 us; speedup vs baseline: 1.0274x; 1.0274x over previous
//
#include <hip/hip_runtime.h>

typedef unsigned short us_t;
typedef short bf16x8 __attribute__((ext_vector_type(8)));
typedef float f32x4 __attribute__((ext_vector_type(4)));

#define E_ACT 200000
#define E_TOT 250000
#define DIR   240
#define C_OLD 0.8944271909999159f
#define C_NEW 0.4472135954999579f
#define S_OH  0.08838834764831845f   // 1/sqrt(128)

// ---- transposed bf16 weight arena offsets (elements) ----
#define WO_W0   0         // [160][352]
#define WO_W1P  56320     // [48][288]
#define WO_W1M  70144     // [48][288]
#define WO_W2P  83968     // [16][96]
#define WO_W2M  85504     // [16][96]
#define WO_GW   87040     // [224][128]
#define WO_EW   115712    // [112][128]
#define WO_A1   130048    // [128][192]
#define WO_A2   154624    // [128][128]
#define WO_A3   171008    // [128][128]
#define WO_B1   187392    // [128][256]
#define WO_B2   220160    // [128][128]
#define WO_B3   236544    // [128][128]
#define WO_O0   252928    // [64][128]
#define WO_O1   261120    // [32][128]
#define WO_O2   265216    // [16][128]
#define WO_P0T  267264    // [64][64]
#define WO_P1T  271360    // [32][32]
#define WO_P2T  272384    // [16][32] (k 16..31 zeroed)
#define W_TOTAL 272896

__device__ __forceinline__ float b2f(us_t u) { return __uint_as_float(((unsigned)u) << 16); }
__device__ __forceinline__ us_t f2b(float f) {
    unsigned x = __float_as_uint(f);
    return (us_t)((x + 0x7fffu + ((x >> 16) & 1u)) >> 16);   // RNE
}
__device__ __forceinline__ float sigm(float x) { return 1.0f / (1.0f + __expf(-x)); }

#define MFMA(a,b,c) __builtin_amdgcn_mfma_f32_16x16x32_bf16((a),(b),(c),0,0,0)

// ============================================================================
// prep: build transposed/padded bf16 weights in workspace
// ============================================================================
__global__ __launch_bounds__(256) void prep_kernel(
    const float* __restrict__ W0, const float* __restrict__ W1r, const float* __restrict__ W1i,
    const float* __restrict__ W2r, const float* __restrict__ W2i,
    const float* __restrict__ Gw, const float* __restrict__ Ew,
    const float* __restrict__ A1, const float* __restrict__ A2, const float* __restrict__ A3,
    const float* __restrict__ B1, const float* __restrict__ B2, const float* __restrict__ B3,
    const float* __restrict__ O0, const float* __restrict__ O1, const float* __restrict__ O2,
    const float* __restrict__ P0w, const float* __restrict__ P1w, const float* __restrict__ P2w,
    us_t* __restrict__ wb)
{
    int idx = blockIdx.x * 256 + threadIdx.x;
    if (idx >= W_TOTAL) return;
    float v;
    if (idx < WO_W1P) {                        // W0T [160][352], pad k 336->352
        int r = idx, n = r / 352, k = r % 352;
        v = (k < 336) ? W0[n * 336 + k] : 0.f;
    } else if (idx < WO_W1M) {                 // [W1r | -W1i]  [48][288]
        int r = idx - WO_W1P, n = r / 288, k = r % 288;
        v = (k < 144) ? W1r[n * 144 + k] : -W1i[n * 144 + (k - 144)];
    } else if (idx < WO_W2P) {                 // [W1i | W1r]
        int r = idx - WO_W1M, n = r / 288, k = r % 288;
        v = (k < 144) ? W1i[n * 144 + k] : W1r[n * 144 + (k - 144)];
    } else if (idx < WO_W2M) {                 // [W2r | -W2i]  [16][96]
        int r = idx - WO_W2P, n = r / 96, k = r % 96;
        v = (k < 48) ? W2r[n * 48 + k] : -W2i[n * 48 + (k - 48)];
    } else if (idx < WO_GW) {                  // [W2i | W2r]
        int r = idx - WO_W2M, n = r / 96, k = r % 96;
        v = (k < 48) ? W2i[n * 48 + k] : W2r[n * 48 + (k - 48)];
    } else if (idx < WO_EW) {                  // GwT [224][128]
        int r = idx - WO_GW, n = r / 128, k = r % 128;
        v = Gw[k * 224 + n];
    } else if (idx < WO_A1) {                  // EwT [112][128]
        int r = idx - WO_EW, n = r / 128, k = r % 128;
        v = Ew[k * 112 + n];
    } else if (idx < WO_A2) {                  // A1T [128][192]
        int r = idx - WO_A1, n = r / 192, k = r % 192;
        v = A1[k * 128 + n];
    } else if (idx < WO_A3) {                  // A2T [128][128]
        int r = idx - WO_A2, n = r / 128, k = r % 128;
        v = A2[k * 128 + n];
    } else if (idx < WO_B1) {                  // A3T
        int r = idx - WO_A3, n = r / 128, k = r % 128;
        v = A3[k * 128 + n];
    } else if (idx < WO_B2) {                  // B1T [128][256]
        int r = idx - WO_B1, n = r / 256, k = r % 256;
        v = B1[k * 128 + n];
    } else if (idx < WO_B3) {                  // B2T
        int r = idx - WO_B2, n = r / 128, k = r % 128;
        v = B2[k * 128 + n];
    } else if (idx < WO_O0) {                  // B3T
        int r = idx - WO_B3, n = r / 128, k = r % 128;
        v = B3[k * 128 + n];
    } else if (idx < WO_O1) {                  // O0 [64][128] already N-major
        v = O0[idx - WO_O0];
    } else if (idx < WO_O2) {
        v = O1[idx - WO_O1];
    } else if (idx < WO_P0T) {
        v = O2[idx - WO_O2];
    } else if (idx < WO_P1T) {                 // P0 [64][64] N-major
        v = P0w[idx - WO_P0T];
    } else if (idx < WO_P2T) {                 // P1 [32][32] N-major
        v = P1w[idx - WO_P1T];
    } else {                                   // P2 [16][32], k>=16 zero
        int r = idx - WO_P2T, n = r / 32, k = r % 32;
        v = (k < 16) ? P2w[n * 16 + k] : 0.f;
    }
    wb[idx] = f2b(v);
}

// ============================================================================
// kcopy: out_lat[row] = latents[row] for INACTIVE rows only.
// ============================================================================
__global__ __launch_bounds__(256) void kcopy_kernel(
    const float* __restrict__ latents, const int* __restrict__ act,
    float* __restrict__ out_lat)
{
    int idx = blockIdx.x * 256 + threadIdx.x;   // E_TOT * 16
    if (idx >= E_TOT * 16) return;
    int row = idx >> 4, part = idx & 15;
    int lo = 0, hi = E_ACT;
    while (lo < hi) {
        int mid = (lo + hi) >> 1;
        if (act[mid] < row) lo = mid + 1; else hi = mid;
    }
    bool active = (lo < E_ACT) && (act[lo] == row);
    if (!active) {
        const float4* src = (const float4*)&latents[(size_t)row * 128 + part * 8];
        float4* dst = (float4*)&out_lat[(size_t)row * 128 + part * 8];
        dst[0] = src[0];
        dst[1] = src[1];
    }
}

// ---- latent A-fragment fetch (global -> regs, bf16) ----
__device__ __forceinline__ void lat_fetch_a(const float* __restrict__ latents,
                                            const int* __restrict__ aes_l,
                                            int lane, bf16x8 a[4])
{
    const int r = lane & 15, g = lane >> 4;
    const float* lp = latents + (size_t)aes_l[r] * 128 + g * 8;
    #pragma unroll
    for (int ks = 0; ks < 4; ++ks) {
        float4 v0 = *(const float4*)(lp + ks * 32);
        float4 v1 = *(const float4*)(lp + ks * 32 + 4);
        bf16x8 av;
        av[0] = (short)f2b(v0.x); av[1] = (short)f2b(v0.y);
        av[2] = (short)f2b(v0.z); av[3] = (short)f2b(v0.w);
        av[4] = (short)f2b(v1.x); av[5] = (short)f2b(v1.y);
        av[6] = (short)f2b(v1.z); av[7] = (short)f2b(v1.w);
        a[ks] = av;
    }
}

// ---- M=32 W0 tile fused with its Gw gate tile ----
__device__ __forceinline__ void gemmW0g32(
    const us_t* __restrict__ in0s, const us_t* __restrict__ wbase,
    const bf16x8 lA[4], const bf16x8 lB[4], const float* __restrict__ Gb,
    int nt, us_t* __restrict__ om0g, int lane)
{
    const int r = lane & 15, g = lane >> 4;
    f32x4 wa = {0.f,0.f,0.f,0.f}, wb = wa, ga = wa, gb = wa;
    const us_t* apA = in0s + r * 360 + g * 8;
    const us_t* apB = in0s + (16 + r) * 360 + g * 8;
    const us_t* wp  = wbase + WO_W0 + (size_t)(nt * 16 + r) * 352 + g * 8;
    #pragma unroll
    for (int ks = 0; ks < 11; ++ks) {
        bf16x8 b = *(const bf16x8*)(wp + ks * 32);
        wa = MFMA(*(const bf16x8*)(apA + ks * 32), b, wa);
        wb = MFMA(*(const bf16x8*)(apB + ks * 32), b, wb);
    }
    const us_t* gp = wbase + WO_GW + (size_t)(nt * 16 + r) * 128 + g * 8;
    #pragma unroll
    for (int ks = 0; ks < 4; ++ks) {
        bf16x8 b = *(const bf16x8*)(gp + ks * 32);
        ga = MFMA(lA[ks], b, ga);
        gb = MFMA(lB[ks], b, gb);
    }
    float bi = Gb[nt * 16 + r];
    #pragma unroll
    for (int i = 0; i < 4; ++i) {
        int eA = g * 4 + i, eB = 16 + g * 4 + i;
        om0g[eA * 162 + nt * 16 + r] = f2b(wa[i] * (ga[i] + bi));
        om0g[eB * 162 + nt * 16 + r] = f2b(wb[i] * (gb[i] + bi));
    }
}

// ---- M=32 W1 tile j (P and M) fused with gate tile ----
__device__ __forceinline__ void gemmW1g32(
    const us_t* __restrict__ cact1, const us_t* __restrict__ wbase,
    const bf16x8 lA[4], const bf16x8 lB[4], const float* __restrict__ Gb,
    int j, us_t* __restrict__ cp1g, us_t* __restrict__ cn1g, int lane)
{
    const int r = lane & 15, g = lane >> 4;
    f32x4 pa = {0.f,0.f,0.f,0.f}, pb = pa, ma = pa, mb = pa, ga = pa, gb = pa;
    const us_t* apA = cact1 + r * 296 + g * 8;
    const us_t* apB = cact1 + (16 + r) * 296 + g * 8;
    const us_t* wpP = wbase + WO_W1P + (size_t)(j * 16 + r) * 288 + g * 8;
    const us_t* wpM = wbase + WO_W1M + (size_t)(j * 16 + r) * 288 + g * 8;
    #pragma unroll
    for (int ks = 0; ks < 9; ++ks) {
        bf16x8 aA = *(const bf16x8*)(apA + ks * 32);
        bf16x8 aB = *(const bf16x8*)(apB + ks * 32);
        bf16x8 bP = *(const bf16x8*)(wpP + ks * 32);
        bf16x8 bM = *(const bf16x8*)(wpM + ks * 32);
        pa = MFMA(aA, bP, pa); pb = MFMA(aB, bP, pb);
        ma = MFMA(aA, bM, ma); mb = MFMA(aB, bM, mb);
    }
    const us_t* gp = wbase + WO_GW + (size_t)(160 + j * 16 + r) * 128 + g * 8;
    #pragma unroll
    for (int ks = 0; ks < 4; ++ks) {
        bf16x8 b = *(const bf16x8*)(gp + ks * 32);
        ga = MFMA(lA[ks], b, ga);
        gb = MFMA(lB[ks], b, gb);
    }
    float bi = Gb[160 + j * 16 + r];
    #pragma unroll
    for (int i = 0; i < 4; ++i) {
        int eA = g * 4 + i, eB = 16 + g * 4 + i;
        float gA = ga[i] + bi, gB = gb[i] + bi;
        cp1g[eA * 50 + j * 16 + r] = f2b(pa[i] * gA);
        cn1g[eA * 50 + j * 16 + r] = f2b(ma[i] * gA);
        cp1g[eB * 50 + j * 16 + r] = f2b(pb[i] * gB);
        cn1g[eB * 50 + j * 16 + r] = f2b(mb[i] * gB);
    }
}

// ---- M=32 W2 (P and M) fused with gate tile ----
__device__ __forceinline__ void gemmW2g32(
    const us_t* __restrict__ cact2, const us_t* __restrict__ wbase,
    const bf16x8 lA[4], const bf16x8 lB[4], const float* __restrict__ Gb,
    us_t* __restrict__ cp2g, us_t* __restrict__ cn2g, int lane)
{
    const int r = lane & 15, g = lane >> 4;
    f32x4 pa = {0.f,0.f,0.f,0.f}, pb = pa, ma = pa, mb = pa, ga = pa, gb = pa;
    const us_t* apA = cact2 + r * 104 + g * 8;
    const us_t* apB = cact2 + (16 + r) * 104 + g * 8;
    const us_t* wpP = wbase + WO_W2P + (size_t)r * 96 + g * 8;
    const us_t* wpM = wbase + WO_W2M + (size_t)r * 96 + g * 8;
    #pragma unroll
    for (int ks = 0; ks < 3; ++ks) {
        bf16x8 aA = *(const bf16x8*)(apA + ks * 32);
        bf16x8 aB = *(const bf16x8*)(apB + ks * 32);
        bf16x8 bP = *(const bf16x8*)(wpP + ks * 32);
        bf16x8 bM = *(const bf16x8*)(wpM + ks * 32);
        pa = MFMA(aA, bP, pa); pb = MFMA(aB, bP, pb);
        ma = MFMA(aA, bM, ma); mb = MFMA(aB, bM, mb);
    }
    const us_t* gp = wbase + WO_GW + (size_t)(208 + r) * 128 + g * 8;
    #pragma unroll
    for (int ks = 0; ks < 4; ++ks) {
        bf16x8 b = *(const bf16x8*)(gp + ks * 32);
        ga = MFMA(lA[ks], b, ga);
        gb = MFMA(lB[ks], b, gb);
    }
    float bi = Gb[208 + r];
    #pragma unroll
    for (int i = 0; i < 4; ++i) {
        int eA = g * 4 + i, eB = 16 + g * 4 + i;
        float gA = ga[i] + bi, gB = gb[i] + bi;
        cp2g[eA * 18 + r] = f2b(pa[i] * gA);
        cn2g[eA * 18 + r] = f2b(ma[i] * gA);
        cp2g[eB * 18 + r] = f2b(pb[i] * gB);
        cn2g[eB * 18 + r] = f2b(mb[i] * gB);
    }
}

// ---- M=32 Ew tile -> wl ----
__device__ __forceinline__ void lat_gemmE32(
    const bf16x8 lA[4], const bf16x8 lB[4],
    const us_t* __restrict__ wgt, const float* __restrict__ bias,
    int nt, us_t* __restrict__ wl, int lane)
{
    const int r = lane & 15, g = lane >> 4;
    f32x4 aA = {0.f,0.f,0.f,0.f}, aB = aA;
    const us_t* wp = wgt + (size_t)(nt * 16 + r) * 128 + g * 8;
    #pragma unroll
    for (int ks = 0; ks < 4; ++ks) {
        bf16x8 b = *(const bf16x8*)(wp + ks * 32);
        aA = MFMA(lA[ks], b, aA);
        aB = MFMA(lB[ks], b, aB);
    }
    float bi = bias[nt * 16 + r];
    #pragma unroll
    for (int i = 0; i < 4; ++i) {
        int eA = g * 4 + i, eB = 16 + g * 4 + i;
        wl[eA * 120 + nt * 16 + r] = f2b(aA[i] + bi);
        wl[eB * 120 + nt * 16 + r] = f2b(aB[i] + bi);
    }
}

// ---- M=32 P-projection ----
template<int KS>
__device__ __forceinline__ void pgemm32(const us_t* __restrict__ actbase, int as,
                                        const us_t* __restrict__ wgt, int kp, int lane,
                                        f32x4& accA, f32x4& accB)
{
    const int r = lane & 15, g = lane >> 4;
    const us_t* apA = actbase + r * as + g * 8;
    const us_t* apB = actbase + (16 + r) * as + g * 8;
    const us_t* wp = wgt + (size_t)r * kp + g * 8;
    #pragma unroll
    for (int ks = 0; ks < KS; ++ks) {
        bf16x8 b = *(const bf16x8*)(wp + ks * 32);
        accA = MFMA(*(const bf16x8*)(apA + ks * 32), b, accA);
        accB = MFMA(*(const bf16x8*)(apB + ks * 32), b, accB);
    }
}

// ---- M=32 MLP layer (R8-proven): 2 n-tiles per wave ----
template<int KS, bool SILU>
__device__ __forceinline__ void mlayer(
    const us_t* __restrict__ actA, const us_t* __restrict__ actB, int split, int as,
    const us_t* __restrict__ wgt, int kp, const float* __restrict__ bias,
    us_t* __restrict__ out, int os, int lane, int w)
{
    const int r = lane & 15, g = lane >> 4;
    const int n0 = 2 * w * 16, n1 = n0 + 16;
    f32x4 a00 = {0.f,0.f,0.f,0.f}, a01 = a00, a10 = a00, a11 = a00;
    const us_t* wp0 = wgt + (size_t)(n0 + r) * kp + g * 8;
    const us_t* wp1 = wgt + (size_t)(n1 + r) * kp + g * 8;
    #pragma unroll
    for (int ks = 0; ks < KS; ++ks) {
        const us_t* ab = (ks < split) ? (actA + ks * 32) : (actB + (ks - split) * 32);
        bf16x8 f0 = *(const bf16x8*)(ab + r * as + g * 8);
        bf16x8 f1 = *(const bf16x8*)(ab + (16 + r) * as + g * 8);
        bf16x8 b0 = *(const bf16x8*)(wp0 + ks * 32);
        bf16x8 b1 = *(const bf16x8*)(wp1 + ks * 32);
        a00 = MFMA(f0, b0, a00); a01 = MFMA(f0, b1, a01);
        a10 = MFMA(f1, b0, a10); a11 = MFMA(f1, b1, a11);
    }
    float bi0 = bias[n0 + r], bi1 = bias[n1 + r];
    #pragma unroll
    for (int i = 0; i < 4; ++i) {
        int eA = g * 4 + i, eB = 16 + g * 4 + i;
        float v;
        v = a00[i] + bi0; if (SILU) v *= sigm(v); out[eA * os + n0 + r] = f2b(v);
        v = a01[i] + bi1; if (SILU) v *= sigm(v); out[eA * os + n1 + r] = f2b(v);
        v = a10[i] + bi0; if (SILU) v *= sigm(v); out[eB * os + n0 + r] = f2b(v);
        v = a11[i] + bi1; if (SILU) v *= sigm(v); out[eB * os + n1 + r] = f2b(v);
    }
}

// ============================================================================
// FUSED kernel: 32 edges / 256 threads. Phases:
//  A gather+rotate | B gate-fused stage1 MFMA | C y-build/D^T/silu
//  D P-proj MFMA (ne->global, scal->LDS) | E LN+x-assembly | F MLP x5+barriers
//  G B3+latent-scatter + O-proj(->LDS) | H edge combine -> out_edge
// LDS 80640B -> 2 blocks/CU.
// ============================================================================
__global__ __launch_bounds__(256, 2) void fused_kernel(
    const float* __restrict__ latents,
    const float* __restrict__ node_features,
    const float* __restrict__ edge_features,
    const float* __restrict__ cutoff,
    const float* __restrict__ one_hot,
    const float* __restrict__ wD1,
    const float* __restrict__ wD2,
    const float* __restrict__ Gb,  const float* __restrict__ Eb,
    const float* __restrict__ P0b,
    const float* __restrict__ ln_g, const float* __restrict__ ln_b,
    const float* __restrict__ A1b, const float* __restrict__ A2b, const float* __restrict__ A3b,
    const float* __restrict__ B1b, const float* __restrict__ B2b, const float* __restrict__ B3b,
    const int* __restrict__ edge_index, const int* __restrict__ active_edges,
    const us_t* __restrict__ wbase,
    us_t* __restrict__ ne_ws,
    float* __restrict__ out_edge, float* __restrict__ out_lat)
{
    __shared__ __align__(16) char smem[80640];
    // region A [0,48640): activations (A,B); z (C,D); MLP buffers (E..H)
    us_t* in0s  = (us_t*)(smem);            // [32][360]
    us_t* cact1 = (us_t*)(smem + 23040);    // [32][296]
    us_t* cact2 = (us_t*)(smem + 41984);    // [32][104]
    us_t* z0l   = (us_t*)(smem);            // [32] stride 72
    us_t* z1l   = (us_t*)(smem + 4608);     // [32] stride 104
    us_t* z2l   = (us_t*)(smem + 11264);    // [32] stride 168
    us_t* x_lds = (us_t*)(smem);            // [32][200] (E..F)
    us_t* h_a   = (us_t*)(smem + 12800);    // [32][136]
    us_t* h_b   = (us_t*)(smem + 21504);    // [32][136]
    us_t* ohl   = (us_t*)(smem + 30208);    // [32][136]
    us_t* ohw_l = (us_t*)(smem + 38912);    // [32][112] (G..H)
    // region B
    float* D1l  = (float*)(smem + 48640);   // [32][12]
    float* D2l  = (float*)(smem + 50176);   // [32][28]
    int*   aes  = (int*)(smem + 53760);     // [32]
    // region D: stage-1 outputs (B..C); scal/cut after
    us_t* om0g  = (us_t*)(smem + 53888);    // [32][162]
    us_t* cp1g  = (us_t*)(smem + 64256);    // [32][50]
    us_t* cn1g  = (us_t*)(smem + 67456);    // [32][50]
    us_t* cp2g  = (us_t*)(smem + 70656);    // [32][18]
    us_t* cn2g  = (us_t*)(smem + 71808);    // [32][18]
    us_t* wl    = (us_t*)(smem + 72960);    // [32][120]
    us_t* scal_l= (us_t*)(smem + 64256);    // [32][64] bf16 (alias cp1g/cn1g, dead after C)
    float* cut_l= (float*)(smem + 53888);   // [32] f32 (alias om0g, dead after C)

    const int t  = threadIdx.x;
    const int e0 = blockIdx.x * 32;
    const int lane = t & 63, w = t >> 6;

    // ---------------- Phase A: register gather + rotate (2 passes) ------------
    #pragma unroll
    for (int ep = 0; ep < 2; ++ep) {
        const int e = (t >> 4) + 16 * ep, l = t & 15;
        const int eg = e0 + e;
        const int ae = active_edges[eg];
        const int ec = edge_index[ae];
        const int en = edge_index[E_TOT + ae];
        if (l == 0) aes[e] = ae;

        float v1  = (l < 9) ? wD1[(size_t)eg * 9 + l] : 0.f;
        float v2a = wD2[(size_t)eg * 25 + l];
        float v2b = (l < 9) ? wD2[(size_t)eg * 25 + 16 + l] : 0.f;
        if (l < 9) D1l[e * 12 + l] = v1;
        D2l[e * 28 + l] = v2a;
        if (l < 9) D2l[e * 28 + 16 + l] = v2b;

        float d1[9], d2[25];
        #pragma unroll
        for (int i = 0; i < 9; ++i)  d1[i] = __shfl(v1, i, 16);
        #pragma unroll
        for (int i = 0; i < 16; ++i) d2[i] = __shfl(v2a, i, 16);
        #pragma unroll
        for (int i = 0; i < 9; ++i)  d2[16 + i] = __shfl(v2b, i, 16);

        const float* pc = node_features + (size_t)ec * DIR;
        const float* pe = edge_features + (size_t)eg * DIR;
        const float* pn = node_features + (size_t)en * DIR;
        us_t* in0 = in0s + e * 360;
        us_t* c1  = cact1 + e * 296;
        us_t* c2  = cact2 + e * 104;

        #pragma unroll
        for (int j = 0; j < 4; ++j) {
            int i = l + 16 * j;
            in0[i]       = f2b(pc[i]);
            in0[64 + i]  = f2b(pe[i]);
            in0[128 + i] = f2b(pn[i]);
        }
        in0[336 + l] = 0;   // zero K-pad 336..351

        #pragma unroll
        for (int jj = 0; jj < 6; ++jj) {
            int u = l + 16 * jj;
            int uu = u & 31;
            const float* sp = (u < 32 ? pc : (u < 64 ? pe : pn)) + 64 + uu * 3;
            float x0 = sp[0], x1 = sp[1], x2 = sp[2];
            float r0 = d1[0] * x0 + d1[1] * x1 + d1[2] * x2;
            float r1 = d1[3] * x0 + d1[4] * x1 + d1[5] * x2;
            float r2 = d1[6] * x0 + d1[7] * x1 + d1[8] * x2;
            c1[144 + u]  = f2b(r0);
            in0[192 + u] = f2b(r1);
            c1[u]        = f2b(r2);
        }
        #pragma unroll
        for (int jj = 0; jj < 3; ++jj) {
            int u = l + 16 * jj;
            int uu = u & 15;
            const float* sp = (u < 16 ? pc : (u < 32 ? pe : pn)) + 160 + uu * 5;
            float x0 = sp[0], x1 = sp[1], x2 = sp[2], x3 = sp[3], x4 = sp[4];
            float r[5];
            #pragma unroll
            for (int i = 0; i < 5; ++i)
                r[i] = d2[i * 5 + 0] * x0 + d2[i * 5 + 1] * x1 + d2[i * 5 + 2] * x2
                     + d2[i * 5 + 3] * x3 + d2[i * 5 + 4] * x4;
            c2[48 + u]   = f2b(r[0]);
            c1[240 + u]  = f2b(r[1]);
            in0[288 + u] = f2b(r[2]);
            c1[96 + u]   = f2b(r[3]);
            c2[u]        = f2b(r[4]);
        }
    }
    __syncthreads();

    // ---------------- Phase B: gate-fused M=32 MFMA GEMMs ---------------------
    {
        bf16x8 lA[4], lB[4];
        lat_fetch_a(latents, aes, lane, lA);
        lat_fetch_a(latents, aes + 16, lane, lB);
        if (w == 0) {
            gemmW0g32(in0s, wbase, lA, lB, Gb, 0, om0g, lane);
            gemmW0g32(in0s, wbase, lA, lB, Gb, 1, om0g, lane);
            gemmW0g32(in0s, wbase, lA, lB, Gb, 2, om0g, lane);
            gemmW1g32(cact1, wbase, lA, lB, Gb, 0, cp1g, cn1g, lane);
        } else if (w == 1) {
            gemmW0g32(in0s, wbase, lA, lB, Gb, 3, om0g, lane);
            gemmW0g32(in0s, wbase, lA, lB, Gb, 4, om0g, lane);
            gemmW0g32(in0s, wbase, lA, lB, Gb, 5, om0g, lane);
            gemmW1g32(cact1, wbase, lA, lB, Gb, 1, cp1g, cn1g, lane);
        } else if (w == 2) {
            gemmW0g32(in0s, wbase, lA, lB, Gb, 6, om0g, lane);
            gemmW0g32(in0s, wbase, lA, lB, Gb, 7, om0g, lane);
            gemmW0g32(in0s, wbase, lA, lB, Gb, 8, om0g, lane);
            gemmW1g32(cact1, wbase, lA, lB, Gb, 2, cp1g, cn1g, lane);
        } else {
            gemmW0g32(in0s, wbase, lA, lB, Gb, 9, om0g, lane);
            gemmW2g32(cact2, wbase, lA, lB, Gb, cp2g, cn2g, lane);
            #pragma unroll
            for (int nt = 0; nt < 7; ++nt)
                lat_gemmE32(lA, lB, wbase + WO_EW, Eb, nt, wl, lane);
        }
    }
    __syncthreads();

    // ---------------- Phase C: y-build + D^T + silu -> z (2 passes) -----------
    #pragma unroll
    for (int ep = 0; ep < 2; ++ep) {
        const int e = (t >> 4) + 16 * ep, l = t & 15;
        const float* D1e = D1l + e * 12;
        const float* D2e = D2l + e * 28;
        #pragma unroll
        for (int uu = 0; uu < 2; ++uu) {
            int u = l + uu * 16;
            float j0 = b2f(cn1g[e * 50 + u]);
            float j1 = b2f(om0g[e * 162 + 112 + u]);
            float j2 = b2f(cp1g[e * 50 + u]);
            float gate = sigm(b2f(om0g[e * 162 + 64 + u]));
            #pragma unroll
            for (int i = 0; i < 3; ++i) {
                float yr = D1e[0 * 3 + i] * j0 + D1e[1 * 3 + i] * j1 + D1e[2 * 3 + i] * j2;
                z1l[e * 104 + i * 32 + u] = f2b(yr * gate);
            }
        }
        {
            int u = l;
            float j0 = b2f(cn2g[e * 18 + u]);
            float j1 = b2f(cn1g[e * 50 + 32 + u]);
            float j2 = b2f(om0g[e * 162 + 144 + u]);
            float j3 = b2f(cp1g[e * 50 + 32 + u]);
            float j4 = b2f(cp2g[e * 18 + u]);
            float gate = sigm(b2f(om0g[e * 162 + 96 + u]));
            #pragma unroll
            for (int i = 0; i < 5; ++i) {
                float yr = D2e[0 * 5 + i] * j0 + D2e[1 * 5 + i] * j1 + D2e[2 * 5 + i] * j2
                         + D2e[3 * 5 + i] * j3 + D2e[4 * 5 + i] * j4;
                z2l[e * 168 + i * 32 + u] = f2b(yr * gate);
                z2l[e * 168 + i * 32 + 16 + u] = 0;
            }
        }
        #pragma unroll
        for (int ii = 0; ii < 4; ++ii) {
            int c = l + 16 * ii;
            float v = b2f(om0g[e * 162 + c]);
            z0l[e * 72 + c] = f2b(v * sigm(v));
        }
    }
    __syncthreads();

    // ---------------- Phase D: P-proj MFMA; ne->global, scal->LDS -------------
    {
        const int r = lane & 15, g = lane >> 4;
        const float sc1 = 0.17677669529663687f;
        if (w < 2) {
            #pragma unroll
            for (int jj = 0; jj < 2; ++jj) {
                int nt = 2 * w + jj;
                f32x4 aA = {0.f,0.f,0.f,0.f}, aB = aA;
                pgemm32<2>(z0l, 72, wbase + WO_P0T + nt * 16 * 64, 64, lane, aA, aB);
                int n = nt * 16 + r;
                float bi = P0b[n];
                #pragma unroll
                for (int i = 0; i < 4; ++i) {
                    int eA = g * 4 + i, eB = 16 + g * 4 + i;
                    float zA = aA[i] * 0.125f + bi;
                    float zB = aB[i] * 0.125f + bi;
                    scal_l[eA * 64 + n] = f2b(zA);
                    scal_l[eB * 64 + n] = f2b(zB);
                    ne_ws[(size_t)(e0 + eA) * 240 + n] = f2b(zA * b2f(wl[eA * 120 + n]));
                    ne_ws[(size_t)(e0 + eB) * 240 + n] = f2b(zB * b2f(wl[eB * 120 + n]));
                }
            }
        } else if (w == 2) {
            #pragma unroll
            for (int m = 0; m < 3; ++m) {
                #pragma unroll
                for (int nt = 0; nt < 2; ++nt) {
                    f32x4 aA = {0.f,0.f,0.f,0.f}, aB = aA;
                    pgemm32<1>(z1l + m * 32, 104, wbase + WO_P1T + nt * 16 * 32, 32,
                               lane, aA, aB);
                    int u = nt * 16 + r;
                    #pragma unroll
                    for (int i = 0; i < 4; ++i) {
                        int eA = g * 4 + i, eB = 16 + g * 4 + i;
                        ne_ws[(size_t)(e0 + eA) * 240 + 64 + u * 3 + m] =
                            f2b(aA[i] * sc1 * b2f(wl[eA * 120 + 64 + u]));
                        ne_ws[(size_t)(e0 + eB) * 240 + 64 + u * 3 + m] =
                            f2b(aB[i] * sc1 * b2f(wl[eB * 120 + 64 + u]));
                    }
                }
            }
        } else if (w == 3) {
            #pragma unroll
            for (int m = 0; m < 5; ++m) {
                f32x4 aA = {0.f,0.f,0.f,0.f}, aB = aA;
                pgemm32<1>(z2l + m * 32, 168, wbase + WO_P2T, 32, lane, aA, aB);
                int u = r;
                #pragma unroll
                for (int i = 0; i < 4; ++i) {
                    int eA = g * 4 + i, eB = 16 + g * 4 + i;
                    ne_ws[(size_t)(e0 + eA) * 240 + 160 + u * 5 + m] =
                        f2b(aA[i] * 0.25f * b2f(wl[eA * 120 + 96 + u]));
                    ne_ws[(size_t)(e0 + eB) * 240 + 160 + u * 5 + m] =
                        f2b(aB[i] * 0.25f * b2f(wl[eB * 120 + 96 + u]));
                }
            }
        }
    }
    __syncthreads();

    // ---------------- Phase E: LN -> x[0:128], scal -> x[128:192], ohl --------
    {
        int ee = t >> 3, l8 = t & 7;
        int ae = aes[ee];
        if (l8 == 0) cut_l[ee] = cutoff[ae];
        const float* lp = latents + (size_t)ae * 128 + l8 * 16;
        float xs[16];
        #pragma unroll
        for (int q = 0; q < 4; ++q) {
            float4 v = *(const float4*)(lp + q * 4);
            xs[q * 4 + 0] = v.x; xs[q * 4 + 1] = v.y;
            xs[q * 4 + 2] = v.z; xs[q * 4 + 3] = v.w;
        }
        float s1 = 0.f, s2 = 0.f;
        #pragma unroll
        for (int i = 0; i < 16; ++i) { s1 += xs[i]; s2 += xs[i] * xs[i]; }
        #pragma unroll
        for (int off = 1; off < 8; off <<= 1) {
            s1 += __shfl_xor(s1, off, 8);
            s2 += __shfl_xor(s2, off, 8);
        }
        float mu  = s1 * (1.f / 128.f);
        float var = s2 * (1.f / 128.f) - mu * mu;
        float rstd = rsqrtf(var + 1e-5f);
        #pragma unroll
        for (int i = 0; i < 16; ++i) {
            int li = l8 * 16 + i;
            x_lds[ee * 200 + li] = f2b((xs[i] - mu) * rstd * ln_g[li] + ln_b[li]);
        }
        // scal -> x[128:192] (2 ushort4 per thread)
        #pragma unroll
        for (int q = 0; q < 2; ++q) {
            int j = l8 * 2 + q;   // 0..15
            *(ushort4*)&x_lds[ee * 200 + 128 + j * 4] =
                *(const ushort4*)&scal_l[ee * 64 + j * 4];
        }
    }
    for (int idx = t; idx < 32 * 32; idx += 256) {
        int ee = idx >> 5, j = idx & 31;
        float4 ov = *(const float4*)&one_hot[(size_t)(e0 + ee) * 128 + j * 4];
        ushort4 s; s.x = f2b(ov.x); s.y = f2b(ov.y); s.z = f2b(ov.z); s.w = f2b(ov.w);
        *(ushort4*)&ohl[ee * 136 + j * 4] = s;
    }
    __syncthreads();

    // ---------------- Phase F: MLP chain ----------------
    mlayer<6, true>(x_lds, x_lds, 6, 200, wbase + WO_A1, 192, A1b, h_a, 136, lane, w);
    __syncthreads();
    mlayer<4, true>(h_a, h_a, 4, 136, wbase + WO_A2, 128, A2b, h_b, 136, lane, w);
    __syncthreads();
    mlayer<4, false>(h_b, h_b, 4, 136, wbase + WO_A3, 128, A3b, h_a, 136, lane, w);
    __syncthreads();
    mlayer<8, true>(h_a, ohl, 4, 136, wbase + WO_B1, 256, B1b, h_b, 136, lane, w);
    __syncthreads();
    mlayer<4, true>(h_b, h_b, 4, 136, wbase + WO_B2, 128, B2b, h_a, 136, lane, w);
    __syncthreads();

    // ---------------- Phase G: B3 + latent scatter; O-proj -> LDS -------------
    {
        const int r = lane & 15, g = lane >> 4;
        const int n0 = 2 * w * 16, n1 = n0 + 16;
        f32x4 a00 = {0.f,0.f,0.f,0.f}, a01 = a00, a10 = a00, a11 = a00;
        const us_t* wp0 = wbase + WO_B3 + (size_t)(n0 + r) * 128 + g * 8;
        const us_t* wp1 = wbase + WO_B3 + (size_t)(n1 + r) * 128 + g * 8;
        #pragma unroll
        for (int ks = 0; ks < 4; ++ks) {
            bf16x8 f0 = *(const bf16x8*)(h_a + ks * 32 + r * 136 + g * 8);
            bf16x8 f1 = *(const bf16x8*)(h_a + ks * 32 + (16 + r) * 136 + g * 8);
            bf16x8 b0 = *(const bf16x8*)(wp0 + ks * 32);
            bf16x8 b1 = *(const bf16x8*)(wp1 + ks * 32);
            a00 = MFMA(f0, b0, a00); a01 = MFMA(f0, b1, a01);
            a10 = MFMA(f1, b0, a10); a11 = MFMA(f1, b1, a11);
        }
        float bi0 = B3b[n0 + r], bi1 = B3b[n1 + r];
        #pragma unroll
        for (int i = 0; i < 4; ++i) {
            int eA = g * 4 + i, eB = 16 + g * 4 + i;
            int aeA = aes[eA], aeB = aes[eB];
            float cA = C_NEW * cut_l[eA], cB = C_NEW * cut_l[eB];
            float* oA = out_lat + (size_t)aeA * 128;
            float* oB = out_lat + (size_t)aeB * 128;
            const float* lA = latents + (size_t)aeA * 128;
            const float* lB = latents + (size_t)aeB * 128;
            oA[n0 + r] = cA * (a00[i] + bi0) + C_OLD * lA[n0 + r];
            oA[n1 + r] = cA * (a01[i] + bi1) + C_OLD * lA[n1 + r];
            oB[n0 + r] = cB * (a10[i] + bi0) + C_OLD * lB[n0 + r];
            oB[n1 + r] = cB * (a11[i] + bi1) + C_OLD * lB[n1 + r];
        }
    }
    {
        const int r = lane & 15, g = lane >> 4;
        const int cnt = (w == 3) ? 1 : 2;
        #pragma unroll
        for (int ii = 0; ii < 2; ++ii) {
            if (ii >= cnt) break;
            int nt = (ii == 0) ? w : w + 4;
            const us_t* wb2 = (nt < 4) ? (wbase + WO_O0 + (size_t)nt * 16 * 128)
                            : (nt < 6) ? (wbase + WO_O1 + (size_t)(nt - 4) * 16 * 128)
                                       : (wbase + WO_O2);
            f32x4 c0 = {0.f,0.f,0.f,0.f}, c1 = c0;
            const us_t* wp = wb2 + (size_t)r * 128 + g * 8;
            #pragma unroll
            for (int ks = 0; ks < 4; ++ks) {
                bf16x8 f0 = *(const bf16x8*)(ohl + ks * 32 + r * 136 + g * 8);
                bf16x8 f1 = *(const bf16x8*)(ohl + ks * 32 + (16 + r) * 136 + g * 8);
                bf16x8 b = *(const bf16x8*)(wp + ks * 32);
                c0 = MFMA(f0, b, c0); c1 = MFMA(f1, b, c1);
            }
            int n = nt * 16 + r;
            #pragma unroll
            for (int i = 0; i < 4; ++i) {
                int eA = g * 4 + i, eB = 16 + g * 4 + i;
                ohw_l[eA * 112 + n] = f2b(c0[i]);
                ohw_l[eB * 112 + n] = f2b(c1[i]);
            }
        }
    }
    __syncthreads();

    // ---------------- Phase H: edge combine -> out_edge ----------------------
    for (int idx = t; idx < 32 * 60; idx += 256) {
        int e = idx / 60;
        int c0 = (idx - e * 60) * 4;
        size_t eg = (size_t)(e0 + e);
        float4 ef = *(const float4*)&edge_features[eg * 240 + c0];
        ushort4 nv = *(const ushort4*)&ne_ws[eg * 240 + c0];
        float nef[4] = {b2f(nv.x), b2f(nv.y), b2f(nv.z), b2f(nv.w)};
        float eff[4] = {ef.x, ef.y, ef.z, ef.w};
        float4 ov;
        float* op = &ov.x;
        #pragma unroll
        for (int j = 0; j < 4; ++j) {
            int c = c0 + j;
            int o;
            if (c < 64)       o = c;
            else if (c < 160) o = 64 + (c - 64) / 3;
            else              o = 96 + (c - 160) / 5;
            float ohv = b2f(ohw_l[e * 112 + o]);
            op[j] = (C_OLD * eff[j] + C_NEW * nef[j]) * (1.f + S_OH * ohv);
        }
        *(float4*)&out_edge[eg * 240 + c0] = ov;
    }
}

// ============================================================================
extern "C" void kernel_launch(void* const* d_in, const int* in_sizes, int n_in,
                              void* d_out, int out_size, void* d_ws, size_t ws_size,
                              hipStream_t stream)
{
    const float* latents  = (const float*)d_in[0];
    const float* node_f   = (const float*)d_in[1];
    const float* edge_f   = (const float*)d_in[2];
    const float* cutoff   = (const float*)d_in[3];
    const float* one_hot  = (const float*)d_in[4];
    const float* wD1      = (const float*)d_in[5];
    const float* wD2      = (const float*)d_in[6];
    const float* W0       = (const float*)d_in[7];
    const float* W1r      = (const float*)d_in[8];
    const float* W1i      = (const float*)d_in[9];
    const float* W2r      = (const float*)d_in[10];
    const float* W2i      = (const float*)d_in[11];
    const float* Gw       = (const float*)d_in[12];
    const float* Gb       = (const float*)d_in[13];
    const float* P0w      = (const float*)d_in[14];
    const float* P0b      = (const float*)d_in[15];
    const float* P1w      = (const float*)d_in[16];
    const float* P2w      = (const float*)d_in[17];
    const float* Ew       = (const float*)d_in[18];
    const float* Eb       = (const float*)d_in[19];
    const float* ln_g     = (const float*)d_in[20];
    const float* ln_b     = (const float*)d_in[21];
    const float* A1       = (const float*)d_in[22];
    const float* A1b      = (const float*)d_in[23];
    const float* A2       = (const float*)d_in[24];
    const float* A2b      = (const float*)d_in[25];
    const float* A3       = (const float*)d_in[26];
    const float* A3b      = (const float*)d_in[27];
    const float* B1       = (const float*)d_in[28];
    const float* B1b      = (const float*)d_in[29];
    const float* B2       = (const float*)d_in[30];
    const float* B2b      = (const float*)d_in[31];
    const float* B3       = (const float*)d_in[32];
    const float* B3b      = (const float*)d_in[33];
    const float* O0       = (const float*)d_in[34];
    const float* O1       = (const float*)d_in[35];
    const float* O2       = (const float*)d_in[36];
    const int* edge_index = (const int*)d_in[37];
    const int* act_e      = (const int*)d_in[38];

    float* out_edge = (float*)d_out;                      // E_ACT*240 f32
    float* out_lat  = out_edge + (size_t)E_ACT * DIR;     // E_TOT*128 f32

    // ws layout (bf16 elements): ne | weights
    us_t* ne_ws   = (us_t*)d_ws;                           // E_ACT*240
    us_t* wbase   = ne_ws + (size_t)E_ACT * DIR;           // W_TOTAL

    prep_kernel<<<dim3((W_TOTAL + 255) / 256), dim3(256), 0, stream>>>(
        W0, W1r, W1i, W2r, W2i, Gw, Ew, A1, A2, A3, B1, B2, B3,
        O0, O1, O2, P0w, P1w, P2w, wbase);

    kcopy_kernel<<<dim3((E_TOT * 16 + 255) / 256), dim3(256), 0, stream>>>(
        latents, act_e, out_lat);

    fused_kernel<<<dim3(E_ACT / 32), dim3(256), 0, stream>>>(
        latents, node_f, edge_f, cutoff, one_hot, wD1, wD2,
        Gb, Eb, P0b, ln_g, ln_b,
        A1b, A2b, A3b, B1b, B2b, B3b,
        edge_index, act_e, wbase, ne_ws, out_edge, out_lat);
}